// Round 2
// baseline (80.279 us; speedup 1.0000x reference)
//
#include <hip/hip_runtime.h>

#define B_PAIRS 2048
#define N_ROWS  4096
#define D_DIM   256
#define INV_T   2.0f
#define N_TILES 528            // 32 diag + 496 strictly-upper (32x32 tile grid)

typedef __attribute__((ext_vector_type(4))) float floatx4;

// ---- workspace layout ----
// [0, 1MB)   : zn8t — fp8 e4m3, K-BLOCKED: segment s holds k=[32s,32s+32) for
//              all rows: byte addr = s*131072 + row*32 + (k&31).
// [1MB,+16KB): S[4096] (fp32, sum_{j!=i} exp(sim_ij))
// then       : posSum (fp32), done (u32 tile-completion ticket)

// ---------- kernel 1: row-normalize fp32 -> fp8 e4m3, K-blocked store -------
// Also zero-inits S, posSum, done.
__global__ __launch_bounds__(256)
void ntx_normalize(const float* __restrict__ z_i,
                   const float* __restrict__ z_j,
                   unsigned* __restrict__ zn8t,  // dword view of K-blocked buf
                   float* __restrict__ S,
                   float* __restrict__ posSum,
                   unsigned* __restrict__ done) {
    const int w    = threadIdx.x >> 6;               // wave 0..3
    const int lane = threadIdx.x & 63;
    const int row  = blockIdx.x * 4 + w;             // 0..4095
    const float* src = (row < B_PAIRS) ? (z_i + (size_t)row * D_DIM)
                                       : (z_j + (size_t)(row - B_PAIRS) * D_DIM);
    const float4 v = *(const float4*)(src + lane * 4);   // k = lane*4 .. +3
    float ss = v.x * v.x + v.y * v.y + v.z * v.z + v.w * v.w;
    #pragma unroll
    for (int off = 32; off > 0; off >>= 1) ss += __shfl_xor(ss, off, 64);
    const float rn = 1.0f / fmaxf(sqrtf(ss), 1e-8f);
    unsigned pk = 0;
    pk = __builtin_amdgcn_cvt_pk_fp8_f32(v.x * rn, v.y * rn, pk, false);
    pk = __builtin_amdgcn_cvt_pk_fp8_f32(v.z * rn, v.w * rn, pk, true);
    // k = lane*4 -> segment s = lane>>3, dword-in-seg = row*8 + (lane&7)
    zn8t[(size_t)(lane >> 3) * 32768 + row * 8 + (lane & 7)] = pk;
    if (lane == 0) S[row] = 0.0f;
    if (blockIdx.x == 0 && threadIdx.x == 0) { *posSum = 0.0f; *done = 0u; }
}

// ---------- kernel 2: upper-triangle sim tiles, DIRECT-FROM-L2 fragments ----
// zn8t is 1 MB -> fully L2-resident. Fragments are loaded straight from
// global (each afr/bfr load = 64 lanes x 8B = one coalesced 512B region),
// eliminating LDS staging, the vmcnt drain, and the only __syncthreads in
// the hot path. LDS usage ~0 -> 4 blocks/CU (was 2).
// Finalize (log-sum + output) fused via last-block ticket (no spin; winner
// block alone computes the loss, so no co-residency assumption).
__global__ __launch_bounds__(256, 4)
void ntx_simtile(const unsigned char* __restrict__ zn8t,
                 float* __restrict__ S,
                 float* __restrict__ posSum,
                 unsigned* __restrict__ done,
                 float* __restrict__ out) {
    __shared__ float pred[4];
    __shared__ int lastFlag;

    // linear block id -> upper-triangle (by, bx), bx >= by
    int t = blockIdx.x, by = 0, rowlen = 32;
    while (t >= rowlen) { t -= rowlen; by++; rowlen--; }
    const int bx = by + t;

    const int tid  = threadIdx.x;
    const int lane = tid & 63;
    const int w    = tid >> 6;           // wave 0..3
    const int wr   = w >> 1;             // wave row strip (0..1)
    const int wc   = w & 1;              // wave col strip (0..1)
    const int quad = lane >> 4;          // 0..3
    const int l16  = lane & 15;

    const int rowA0 = by * 128;
    const int rowB0 = bx * 128;
    const bool isDiag = (by == bx);
    const bool isPos  = (rowB0 == (rowA0 ^ B_PAIRS));

    // per-lane byte offsets within a K-segment (row*32 + quad*8)
    const size_t aoff = (size_t)(rowA0 + wr * 64 + l16) * 32 + quad * 8;
    const size_t boff = (size_t)(rowB0 + wc * 64 + l16) * 32 + quad * 8;

    floatx4 acc[4][4];
    #pragma unroll
    for (int i = 0; i < 4; i++)
        #pragma unroll
        for (int j = 0; j < 4; j++)
            acc[i][j] = (floatx4){0.f, 0.f, 0.f, 0.f};

    #pragma unroll
    for (int s = 0; s < 8; s++) {        // K-steps; frag k = s*32 + quad*8 + j
        const unsigned char* bA = zn8t + (size_t)s * 131072 + aoff;
        const unsigned char* bB = zn8t + (size_t)s * 131072 + boff;
        long afr[4], bfr[4];
        #pragma unroll
        for (int fi = 0; fi < 4; fi++)   // fi*16 rows * 32 B = 512 (imm offset)
            afr[fi] = *(const long*)(const void*)(bA + fi * 512);
        #pragma unroll
        for (int fj = 0; fj < 4; fj++)
            bfr[fj] = *(const long*)(const void*)(bB + fj * 512);
        #pragma unroll
        for (int fi = 0; fi < 4; fi++)
            #pragma unroll
            for (int fj = 0; fj < 4; fj++)
                acc[fi][fj] = __builtin_amdgcn_mfma_f32_16x16x32_fp8_fp8(
                    afr[fi], bfr[fj], acc[fi][fj], 0, 0, 0);
    }

    // Epilogue. C/D layout: col=l16, row=quad*4+reg.
    float cs[4] = {0.f, 0.f, 0.f, 0.f};
    float psum = 0.f;
    #pragma unroll
    for (int fi = 0; fi < 4; fi++) {
        float rs[4] = {0.f, 0.f, 0.f, 0.f};
        #pragma unroll
        for (int fj = 0; fj < 4; fj++) {
            const int rj = wc * 64 + fj * 16 + l16;
            #pragma unroll
            for (int reg = 0; reg < 4; reg++) {
                const int ri = wr * 64 + fi * 16 + quad * 4 + reg;
                const float v = acc[fi][fj][reg] * INV_T;
                const bool d = (ri == rj);
                if (isPos && d) psum += 2.0f * v;
                const float e = (isDiag && d) ? 0.f : __expf(v);
                rs[reg] += e;
                cs[fj]  += e;
            }
        }
        #pragma unroll
        for (int reg = 0; reg < 4; reg++) {
            float r = rs[reg];
            r += __shfl_xor(r, 1, 16);
            r += __shfl_xor(r, 2, 16);
            r += __shfl_xor(r, 4, 16);
            r += __shfl_xor(r, 8, 16);
            if (l16 == 0)
                atomicAdd(&S[rowA0 + wr * 64 + fi * 16 + quad * 4 + reg], r);
        }
    }
    if (!isDiag) {
        #pragma unroll
        for (int fj = 0; fj < 4; fj++) {
            float c = cs[fj];
            c += __shfl_xor(c, 16, 64);
            c += __shfl_xor(c, 32, 64);
            if (quad == 0)
                atomicAdd(&S[rowB0 + wc * 64 + fj * 16 + l16], c);
        }
    }
    if (isPos) {
        psum += __shfl_xor(psum, 1, 64);  psum += __shfl_xor(psum, 2, 64);
        psum += __shfl_xor(psum, 4, 64);  psum += __shfl_xor(psum, 8, 64);
        psum += __shfl_xor(psum, 16, 64); psum += __shfl_xor(psum, 32, 64);
        if (lane == 0) pred[w] = psum;
        __syncthreads();
        if (tid == 0)
            atomicAdd(posSum, pred[0] + pred[1] + pred[2] + pred[3]);
    }

    // ---- fused finalize: last tile-block computes the loss ----
    __syncthreads();                     // all waves' atomics vmcnt-drained
    if (tid == 0) {
        __threadfence();                 // S/posSum adds visible before ticket
        lastFlag = (atomicAdd(done, 1u) == N_TILES - 1) ? 1 : 0;
    }
    __syncthreads();
    if (!lastFlag) return;
    __threadfence();                     // acquire side
    float a = 0.f;
    #pragma unroll
    for (int c = 0; c < 16; c++) {       // 256 threads x 16 = 4096 rows
        const float sv = __hip_atomic_load(&S[tid + c * 256],
                                           __ATOMIC_RELAXED,
                                           __HIP_MEMORY_SCOPE_AGENT);
        a += __logf(sv);
    }
    #pragma unroll
    for (int off = 32; off > 0; off >>= 1) a += __shfl_xor(a, off, 64);
    if (lane == 0) pred[w] = a;
    __syncthreads();
    if (tid == 0) {
        const float ps = __hip_atomic_load(posSum, __ATOMIC_RELAXED,
                                           __HIP_MEMORY_SCOPE_AGENT);
        out[0] = (pred[0] + pred[1] + pred[2] + pred[3] - ps) / (float)N_ROWS;
    }
}

extern "C" void kernel_launch(void* const* d_in, const int* in_sizes, int n_in,
                              void* d_out, int out_size, void* d_ws, size_t ws_size,
                              hipStream_t stream) {
    const float* z_i = (const float*)d_in[0];
    const float* z_j = (const float*)d_in[1];
    float* out = (float*)d_out;

    unsigned char* zn8t = (unsigned char*)d_ws;
    float* S        = (float*)((char*)d_ws + (size_t)N_ROWS * D_DIM);  // 1 MB
    float* posSum   = S + N_ROWS;
    unsigned* done  = (unsigned*)(posSum + 1);

    ntx_normalize<<<N_ROWS / 4, 256, 0, stream>>>(z_i, z_j, (unsigned*)zn8t,
                                                  S, posSum, done);
    ntx_simtile<<<N_TILES, 256, 0, stream>>>(zn8t, S, posSum, done, out);
}